// Round 6
// baseline (120.543 us; speedup 1.0000x reference)
//
#include <hip/hip_runtime.h>

#define OC 1024
#define ICN 1024
#define KK 9
#define CH (ICN * KK)      // 9216 floats per channel
#define CH4 (CH / 4)       // 2304 float4
#define BT 512             // 8 waves/block, 4 blocks/CU (exact fit: 1024 blocks)
#define KMB 2048           // kmax blocks (fallback path)

// ws layout (fused path): [0,4) spin counter; [256, 256+4096) part[1024]
#define WS_PART_OFF 64     // in floats

// ============================================================================
// Fused single-launch kernel with spin grid barrier (graph-capturable).
// Phase A: coalesced stage-in + block absmax -> part[oc]; spin barrier.
// Phase B: global max reduce (L2-hot), quant/stage1/stage2, coalesced store.
// Arithmetic identical to the R5 squant kernel (verified absmax 0.0).
// ============================================================================
__global__ void __launch_bounds__(BT, 8) fused_kernel(const float* __restrict__ x,
                                                      float* __restrict__ out,
                                                      unsigned* __restrict__ ctr,
                                                      float* __restrict__ part) {
    __shared__ __align__(16) unsigned char s_mem[CH * 4];  // 36 KB, phase-overlaid
    __shared__ float s_mx[8];
    float* s_x   = (float*)s_mem;
    short* s_q   = (short*)s_mem;                  // bytes [0, 18432)
    float* s_res = (float*)(s_mem + 18432);        // [18432, 22528)
    float* s_pr  = (float*)(s_mem + 22528);        // [22528, 26624)
    int*   s_me  = (int*)(s_mem + 26624);          // [26624, 30720)

    const int oc = blockIdx.x;
    const int t  = threadIdx.x;
    const long long ocbase = (long long)oc * CH;

    // ---- phase A: stage-in (coalesced) + register absmax ----
    const float4* x4 = (const float4*)(x + ocbase);
    float4* s4 = (float4*)s_mem;
    float m = 0.f;
    #pragma unroll
    for (int k = 0; k < 4; ++k) {
        float4 v = x4[t + BT * k];
        s4[t + BT * k] = v;
        m = fmaxf(m, fmaxf(fmaxf(fabsf(v.x), fabsf(v.y)), fmaxf(fabsf(v.z), fabsf(v.w))));
    }
    if (t < CH4 - 4 * BT) {                        // 256 tail float4s
        float4 v = x4[4 * BT + t];
        s4[4 * BT + t] = v;
        m = fmaxf(m, fmaxf(fmaxf(fabsf(v.x), fabsf(v.y)), fmaxf(fabsf(v.z), fabsf(v.w))));
    }
    #pragma unroll
    for (int off = 32; off > 0; off >>= 1)
        m = fmaxf(m, __shfl_xor(m, off, 64));
    if ((t & 63) == 0) s_mx[t >> 6] = m;
    __syncthreads();

    // ---- spin grid barrier (all 1024 blocks co-resident by construction) ----
    if (t == 0) {
        m = s_mx[0];
        #pragma unroll
        for (int w = 1; w < 8; ++w) m = fmaxf(m, s_mx[w]);
        __hip_atomic_store(&part[oc], m, __ATOMIC_RELEASE, __HIP_MEMORY_SCOPE_AGENT);
        __hip_atomic_fetch_add(ctr, 1u, __ATOMIC_ACQ_REL, __HIP_MEMORY_SCOPE_AGENT);
        while (__hip_atomic_load(ctr, __ATOMIC_ACQUIRE, __HIP_MEMORY_SCOPE_AGENT) < (unsigned)OC)
            __builtin_amdgcn_s_sleep(8);
    }
    __syncthreads();

    // ---- global max from 1024 partials (agent-scope loads bypass stale L1) ----
    float gm = fmaxf(
        __hip_atomic_load(&part[t], __ATOMIC_RELAXED, __HIP_MEMORY_SCOPE_AGENT),
        __hip_atomic_load(&part[t + BT], __ATOMIC_RELAXED, __HIP_MEMORY_SCOPE_AGENT));
    #pragma unroll
    for (int off = 32; off > 0; off >>= 1)
        gm = fmaxf(gm, __shfl_xor(gm, off, 64));
    __syncthreads();                               // s_mx reuse hazard
    if ((t & 63) == 0) s_mx[t >> 6] = gm;
    __syncthreads();
    gm = s_mx[0];
    #pragma unroll
    for (int w = 1; w < 8; ++w) gm = fmaxf(gm, s_mx[w]);
    const float scale = gm / 127.0f;
    const float iscale = 1.0f / scale;  // mul not div: verified bit-identical (R3-R5 absmax 0.0)

    // ---- stage 1 from LDS floats; results held in registers ----
    float rn2[2][KK];
    unsigned flip2[2];
    float res2[2], pr2[2], sg2[2];
    int me2[2];
    #pragma unroll
    for (int half = 0; half < 2; ++half) {
        const int row = t + half * BT;
        float re[KK];
        float e = 0.f;
        #pragma unroll
        for (int k = 0; k < KK; ++k) {
            float q = s_x[row * KK + k] * iscale;   // stride-9 dwords: 2 lanes/bank, free
            q = fminf(fmaxf(q, -127.f), 127.f);
            float r = rintf(q);                     // round half to even
            rn2[half][k] = r;
            re[k] = r - q;
            e += re[k];
        }
        int nf = (int)rintf(fabsf(e));
        bool up = e < 0.f;
        unsigned flipped = 0u;
        int bidx = -1;
        float b_re = 0.f;
        for (int f = 0; f < nf; ++f) {
            float bp = 0.f; int bk = -1; float cre = 0.f;
            #pragma unroll
            for (int k = 0; k < KK; ++k) {
                bool cand = up ? (re[k] < 0.f) : (re[k] > 0.f);
                float p = (cand && !((flipped >> k) & 1u)) ? fabsf(re[k]) : 0.f;
                if (p > bp) { bp = p; bk = k; cre = re[k]; }  // strict >: lowest idx wins ties
            }
            if (bk < 0) break;  // safety
            flipped |= (1u << bk);
            bidx = bk; b_re = cre;
        }
        float sgn = up ? 1.f : -1.f;
        flip2[half] = flipped;
        sg2[half] = sgn;
        res2[half] = e + sgn * (float)__popc(flipped);
        if (bidx >= 0) {
            pr2[half] = fabsf(b_re + sgn);
            me2[half] = (row * KK + bidx) | ((up ? 1 : 0) << 16);
        } else {
            pr2[half] = 0.f;
            me2[half] = 0;
        }
    }
    __syncthreads();  // all x reads done before overlay clobbers s_mem

    #pragma unroll
    for (int half = 0; half < 2; ++half) {
        const int row = t + half * BT;
        #pragma unroll
        for (int k = 0; k < KK; ++k)
            s_q[row * KK + k] =
                (short)(int)(rn2[half][k] + (((flip2[half] >> k) & 1u) ? sg2[half] : 0.f));
        s_res[row] = res2[half];
        s_pr[row]  = pr2[half];
        s_me[row]  = me2[half];
    }
    __syncthreads();

    // ---- stage 2: wave 0 only ----
    if (t < 64) {
        float s = 0.f;
        #pragma unroll
        for (int i = 0; i < ICN / 64; ++i) s += s_res[t + i * 64];
        #pragma unroll
        for (int off = 32; off > 0; off >>= 1) s += __shfl_xor(s, off, 64);

        int n2 = (int)rintf(fabsf(s));
        bool up2 = s < 0.f;
        if (n2 > 0) {
            float p[ICN / 64];
            #pragma unroll
            for (int i = 0; i < ICN / 64; ++i) {
                int r = t + i * 64;
                float pr = s_pr[r];
                int dir = s_me[r] >> 16;
                bool match = ((dir != 0) != up2);
                p[i] = (pr > 0.f && match) ? pr : 0.f;
            }
            int f = 0;
            for (; f < n2; ++f) {
                float bp = 0.f; int brow = ICN;
                #pragma unroll
                for (int i = 0; i < ICN / 64; ++i)
                    if (p[i] > bp) { bp = p[i]; brow = t + i * 64; }
                #pragma unroll
                for (int off = 32; off > 0; off >>= 1) {
                    float op = __shfl_xor(bp, off, 64);
                    int  orow = __shfl_xor(brow, off, 64);
                    if (op > bp || (op == bp && orow < brow)) { bp = op; brow = orow; }
                }
                if (bp <= 0.f) break;
                if (t == (brow & 63)) {
                    #pragma unroll
                    for (int i = 0; i < ICN / 64; ++i)
                        if (i == (brow >> 6)) p[i] = 0.f;
                }
                if (t == 0) {
                    int meta = s_me[brow];
                    int gid = meta & 0xFFFF;
                    s_q[gid] = (short)(s_q[gid] + ((meta >> 16) ? -1 : 1));
                }
            }
            if (f < n2) {  // dead overflow path; deviation <= 1 step
                int remaining = n2 - f;
                if (remaining > CH) remaining = CH;
                for (int j = t; j < remaining; j += 64) {
                    float q = x[ocbase + j] * iscale;
                    q = fminf(fmaxf(q, -127.f), 127.f);
                    float r = rintf(q);
                    float rr = r - q;
                    float v = up2 ? ((rr < 0.f) ? r + 1.f : r)
                                  : ((rr > 0.f) ? r - 1.f : r);
                    s_q[j] = (short)(int)v;
                }
            }
        }
    }
    __syncthreads();

    // ---- coalesced stage-out ----
    const short4* q4 = (const short4*)s_mem;
    float4* o4 = (float4*)(out + ocbase);
    #pragma unroll
    for (int k = 0; k < 4; ++k) {
        short4 v = q4[t + BT * k];
        float4 o;
        o.x = (float)v.x * scale;
        o.y = (float)v.y * scale;
        o.z = (float)v.z * scale;
        o.w = (float)v.w * scale;
        o4[t + BT * k] = o;
    }
    if (t < CH4 - 4 * BT) {
        short4 v = q4[4 * BT + t];
        float4 o;
        o.x = (float)v.x * scale;
        o.y = (float)v.y * scale;
        o.z = (float)v.z * scale;
        o.w = (float)v.w * scale;
        o4[4 * BT + t] = o;
    }
}

// ============================================================================
// Fallback path (R5, verified exact): kmax + squant
// ============================================================================
__global__ void __launch_bounds__(256, 8) kmax_part(const float* __restrict__ x,
                                                    float* __restrict__ part) {
    __shared__ float s_m[4];
    const int tid = blockIdx.x * 256 + threadIdx.x;
    const int stride = KMB * 256;
    const float4* x4 = (const float4*)x;
    float m = 0.f;
    #pragma unroll
    for (int k = 0; k < 4; ++k) {
        float4 v = x4[tid + k * stride];
        m = fmaxf(m, fmaxf(fmaxf(fabsf(v.x), fabsf(v.y)), fmaxf(fabsf(v.z), fabsf(v.w))));
    }
    if (tid < (CH4 * OC - 4 * stride)) {
        float4 v = x4[tid + 4 * stride];
        m = fmaxf(m, fmaxf(fmaxf(fabsf(v.x), fabsf(v.y)), fmaxf(fabsf(v.z), fabsf(v.w))));
    }
    #pragma unroll
    for (int off = 32; off > 0; off >>= 1)
        m = fmaxf(m, __shfl_xor(m, off, 64));
    if ((threadIdx.x & 63) == 0) s_m[threadIdx.x >> 6] = m;
    __syncthreads();
    if (threadIdx.x == 0)
        part[blockIdx.x] = fmaxf(fmaxf(s_m[0], s_m[1]), fmaxf(s_m[2], s_m[3]));
}

__global__ void __launch_bounds__(BT, 8) squant_kernel(const float* __restrict__ x,
                                                       float* __restrict__ out,
                                                       const float* __restrict__ part,
                                                       int nparts) {
    __shared__ __align__(16) unsigned char s_mem[CH * 4];
    __shared__ float s_mx[8];
    float* s_x   = (float*)s_mem;
    short* s_q   = (short*)s_mem;
    float* s_res = (float*)(s_mem + 18432);
    float* s_pr  = (float*)(s_mem + 22528);
    int*   s_me  = (int*)(s_mem + 26624);

    const int oc = blockIdx.x;
    const int t  = threadIdx.x;
    const long long ocbase = (long long)oc * CH;

    const float4* x4 = (const float4*)(x + ocbase);
    float4* s4 = (float4*)s_mem;
    #pragma unroll
    for (int k = 0; k < 4; ++k) s4[t + BT * k] = x4[t + BT * k];
    if (t < CH4 - 4 * BT) s4[4 * BT + t] = x4[4 * BT + t];

    float m = fmaxf(fmaxf(part[t], part[t + BT]),
                    fmaxf(part[t + 2 * BT], part[t + 3 * BT]));
    #pragma unroll
    for (int off = 32; off > 0; off >>= 1)
        m = fmaxf(m, __shfl_xor(m, off, 64));
    if ((t & 63) == 0) s_mx[t >> 6] = m;
    __syncthreads();
    float gm = s_mx[0];
    #pragma unroll
    for (int w = 1; w < 8; ++w) gm = fmaxf(gm, s_mx[w]);
    const float scale = gm / 127.0f;
    const float iscale = 1.0f / scale;

    float rn2[2][KK];
    unsigned flip2[2];
    float res2[2], pr2[2], sg2[2];
    int me2[2];
    #pragma unroll
    for (int half = 0; half < 2; ++half) {
        const int row = t + half * BT;
        float re[KK];
        float e = 0.f;
        #pragma unroll
        for (int k = 0; k < KK; ++k) {
            float q = s_x[row * KK + k] * iscale;
            q = fminf(fmaxf(q, -127.f), 127.f);
            float r = rintf(q);
            rn2[half][k] = r;
            re[k] = r - q;
            e += re[k];
        }
        int nf = (int)rintf(fabsf(e));
        bool up = e < 0.f;
        unsigned flipped = 0u;
        int bidx = -1;
        float b_re = 0.f;
        for (int f = 0; f < nf; ++f) {
            float bp = 0.f; int bk = -1; float cre = 0.f;
            #pragma unroll
            for (int k = 0; k < KK; ++k) {
                bool cand = up ? (re[k] < 0.f) : (re[k] > 0.f);
                float p = (cand && !((flipped >> k) & 1u)) ? fabsf(re[k]) : 0.f;
                if (p > bp) { bp = p; bk = k; cre = re[k]; }
            }
            if (bk < 0) break;
            flipped |= (1u << bk);
            bidx = bk; b_re = cre;
        }
        float sgn = up ? 1.f : -1.f;
        flip2[half] = flipped;
        sg2[half] = sgn;
        res2[half] = e + sgn * (float)__popc(flipped);
        if (bidx >= 0) {
            pr2[half] = fabsf(b_re + sgn);
            me2[half] = (row * KK + bidx) | ((up ? 1 : 0) << 16);
        } else {
            pr2[half] = 0.f;
            me2[half] = 0;
        }
    }
    __syncthreads();

    #pragma unroll
    for (int half = 0; half < 2; ++half) {
        const int row = t + half * BT;
        #pragma unroll
        for (int k = 0; k < KK; ++k)
            s_q[row * KK + k] =
                (short)(int)(rn2[half][k] + (((flip2[half] >> k) & 1u) ? sg2[half] : 0.f));
        s_res[row] = res2[half];
        s_pr[row]  = pr2[half];
        s_me[row]  = me2[half];
    }
    __syncthreads();

    if (t < 64) {
        float s = 0.f;
        #pragma unroll
        for (int i = 0; i < ICN / 64; ++i) s += s_res[t + i * 64];
        #pragma unroll
        for (int off = 32; off > 0; off >>= 1) s += __shfl_xor(s, off, 64);

        int n2 = (int)rintf(fabsf(s));
        bool up2 = s < 0.f;
        if (n2 > 0) {
            float p[ICN / 64];
            #pragma unroll
            for (int i = 0; i < ICN / 64; ++i) {
                int r = t + i * 64;
                float pr = s_pr[r];
                int dir = s_me[r] >> 16;
                bool match = ((dir != 0) != up2);
                p[i] = (pr > 0.f && match) ? pr : 0.f;
            }
            int f = 0;
            for (; f < n2; ++f) {
                float bp = 0.f; int brow = ICN;
                #pragma unroll
                for (int i = 0; i < ICN / 64; ++i)
                    if (p[i] > bp) { bp = p[i]; brow = t + i * 64; }
                #pragma unroll
                for (int off = 32; off > 0; off >>= 1) {
                    float op = __shfl_xor(bp, off, 64);
                    int  orow = __shfl_xor(brow, off, 64);
                    if (op > bp || (op == bp && orow < brow)) { bp = op; brow = orow; }
                }
                if (bp <= 0.f) break;
                if (t == (brow & 63)) {
                    #pragma unroll
                    for (int i = 0; i < ICN / 64; ++i)
                        if (i == (brow >> 6)) p[i] = 0.f;
                }
                if (t == 0) {
                    int meta = s_me[brow];
                    int gid = meta & 0xFFFF;
                    s_q[gid] = (short)(s_q[gid] + ((meta >> 16) ? -1 : 1));
                }
            }
            if (f < n2) {
                int remaining = n2 - f;
                if (remaining > CH) remaining = CH;
                for (int j = t; j < remaining; j += 64) {
                    float q = x[ocbase + j] * iscale;
                    q = fminf(fmaxf(q, -127.f), 127.f);
                    float r = rintf(q);
                    float rr = r - q;
                    float v = up2 ? ((rr < 0.f) ? r + 1.f : r)
                                  : ((rr > 0.f) ? r - 1.f : r);
                    s_q[j] = (short)(int)v;
                }
            }
        }
    }
    __syncthreads();

    const short4* q4 = (const short4*)s_mem;
    float4* o4 = (float4*)(out + ocbase);
    #pragma unroll
    for (int k = 0; k < 4; ++k) {
        short4 v = q4[t + BT * k];
        float4 o;
        o.x = (float)v.x * scale;
        o.y = (float)v.y * scale;
        o.z = (float)v.z * scale;
        o.w = (float)v.w * scale;
        o4[t + BT * k] = o;
    }
    if (t < CH4 - 4 * BT) {
        short4 v = q4[4 * BT + t];
        float4 o;
        o.x = (float)v.x * scale;
        o.y = (float)v.y * scale;
        o.z = (float)v.z * scale;
        o.w = (float)v.w * scale;
        o4[4 * BT + t] = o;
    }
}

extern "C" void kernel_launch(void* const* d_in, const int* in_sizes, int n_in,
                              void* d_out, int out_size, void* d_ws, size_t ws_size,
                              hipStream_t stream) {
    const float* x = (const float*)d_in[0];
    float* out = (float*)d_out;

    // Capture-safe pure query: fused path only if 4 blocks/CU guaranteed
    // (spin barrier requires all 1024 blocks co-resident: 256 CU x 4).
    int maxb = 0;
    hipError_t qe = hipOccupancyMaxActiveBlocksPerMultiprocessor(&maxb, fused_kernel, BT, 0);
    bool fused_ok = (qe == hipSuccess) && (maxb >= 4) &&
                    (ws_size >= (WS_PART_OFF + OC) * sizeof(float));

    if (fused_ok) {
        unsigned* ctr = (unsigned*)d_ws;
        float* part = (float*)d_ws + WS_PART_OFF;
        hipMemsetAsync(d_ws, 0, sizeof(unsigned), stream);  // ws re-poisoned 0xAA each launch
        fused_kernel<<<OC, BT, 0, stream>>>(x, out, ctr, part);
        return;
    }

    // Fallback: two-kernel path (R5, verified exact)
    float* part = (float*)d_ws;
    kmax_part<<<KMB, 256, 0, stream>>>(x, part);
    squant_kernel<<<OC, BT, 0, stream>>>(x, out, part, KMB);
}